// Round 2
// baseline (20.998 us; speedup 1.0000x reference)
//
#include <hip/hip_runtime.h>

// ConstructKernel3d: trilinear scatter of W into a 7x7x7 cube per (oc,icg) pair.
// out[o,c,l,j,i] = sum_k W[o,c,k] * wA(l; P0) * wB(j; P2) * wC(i; P1)
// where each axis weight is nonzero only at floor(p)+{0,1} (linear interp).

#define OC   128
#define ICG  128
#define KC   16
#define NPAIR (OC * ICG)          // 16384
#define NPK   (NPAIR * KC)        // 262144 elements per P-plane
#define CUBE  343                 // 7*7*7
#define CUBE_PAD 352              // pad to avoid systematic bank alignment
#define GP    16                  // (o,c) pairs per block -> 256 scatter tasks

__global__ __launch_bounds__(256)
void construct3d_scatter(const float* __restrict__ W,
                         const float* __restrict__ P,
                         float* __restrict__ out)
{
    __shared__ float acc[GP * CUBE_PAD];
    const int tid = threadIdx.x;
    const int blk = blockIdx.x;

    // 1) zero the per-block accumulators (16 x 343, padded)
    #pragma unroll
    for (int e = tid; e < GP * CUBE_PAD; e += 256) acc[e] = 0.0f;
    __syncthreads();

    // 2) scatter: task tid -> pair p = tid>>4, k = tid&15.
    //    Global flat index (pair_global*16 + k) == blk*256 + tid -> coalesced loads.
    {
        const int gidx = blk * 256 + tid;
        const float w  = W[gidx];
        const float p0 = P[gidx]           + 3.0f;  // axis l
        const float p1 = P[NPK + gidx]     + 3.0f;  // axis i
        const float p2 = P[2 * NPK + gidx] + 3.0f;  // axis j

        const float f0 = floorf(p0), f1 = floorf(p1), f2 = floorf(p2);
        const float r0 = p0 - f0, r1 = p1 - f1, r2 = p2 - f2;
        const int lf = (int)f0;
        const int if_ = (int)f1;
        const int jf = (int)f2;

        const float wl[2] = {1.0f - r0, r0};
        const float wi[2] = {1.0f - r1, r1};
        const float wj[2] = {1.0f - r2, r2};

        float* a = &acc[(tid >> 4) * CUBE_PAD];

        #pragma unroll
        for (int dl = 0; dl < 2; ++dl) {
            const int l = lf + dl;
            if ((unsigned)l > 6u) continue;
            #pragma unroll
            for (int dj = 0; dj < 2; ++dj) {
                const int j = jf + dj;
                if ((unsigned)j > 6u) continue;
                const float wlj = w * wl[dl] * wj[dj];
                #pragma unroll
                for (int di = 0; di < 2; ++di) {
                    const int i = if_ + di;
                    if ((unsigned)i > 6u) continue;
                    atomicAdd(&a[l * 49 + j * 7 + i], wlj * wi[di]);
                }
            }
        }
    }
    __syncthreads();

    // 3) stream accumulators to global, fully coalesced dword stores.
    const int base = blk * (GP * CUBE);
    for (int e = tid; e < GP * CUBE; e += 256) {
        const int p   = e / CUBE;          // compiler: magic-mul
        const int off = e - p * CUBE;
        out[base + e] = acc[p * CUBE_PAD + off];
    }
}

extern "C" void kernel_launch(void* const* d_in, const int* in_sizes, int n_in,
                              void* d_out, int out_size, void* d_ws, size_t ws_size,
                              hipStream_t stream)
{
    const float* W = (const float*)d_in[0];   // [128,128,16]
    const float* P = (const float*)d_in[1];   // [3,128,128,16]
    float* out = (float*)d_out;               // [128,128,7,7,7]

    const int grid = NPAIR / GP;              // 1024 blocks
    construct3d_scatter<<<grid, 256, 0, stream>>>(W, P, out);
}

// Round 3
// 19.897 us; speedup vs baseline: 1.0553x; 1.0553x over previous
//
#include <hip/hip_runtime.h>

// ConstructKernel3d: trilinear scatter of W into a 7x7x7 cube per (oc,icg) pair.
// out[o,c,l,j,i] = sum_k W[o,c,k] * wA(l; P0) * wB(j; P2) * wC(i; P1)
// Axis weights nonzero only at floor(p)+{0,1}. Scatter <=8 corners per (o,c,k).
//
// Layout: 16 pairs/block, LDS accumulator stride == CUBE (343) so the flat LDS
// index equals the flat output index -> store phase is a pure float4 stream.
// Each wave owns 4 pairs (lanes 16p..16p+15 scatter pair p) -> all phases are
// wave-contiguous; barriers retained for ordering safety only.

#define OC    128
#define ICG   128
#define KC    16
#define NPAIR (OC * ICG)          // 16384
#define NPK   (NPAIR * KC)        // 262144 elements per P-plane
#define CUBE  343                 // 7*7*7
#define GP    16                  // (o,c) pairs per block -> 256 scatter tasks

__global__ __launch_bounds__(256)
void construct3d_scatter(const float* __restrict__ W,
                         const float* __restrict__ P,
                         float* __restrict__ out)
{
    __shared__ float acc[GP * CUBE];          // 5488 floats = 21952 B
    const int tid  = threadIdx.x;
    const int blk  = blockIdx.x;
    const int wid  = tid >> 6;                // wave 0..3
    const int lane = tid & 63;

    float* wacc = &acc[wid * 4 * CUBE];       // this wave's 1372-float region

    // 1) zero own region, float4 (343 float4s per wave, 16B-aligned)
    const float4 z = {0.f, 0.f, 0.f, 0.f};
    #pragma unroll
    for (int it = 0; it < 6; ++it) {
        const int idx = lane + it * 64;
        if (it < 5 || idx < 343)
            *reinterpret_cast<float4*>(&wacc[idx * 4]) = z;
    }
    __syncthreads();

    // 2) scatter: task tid -> local pair p = tid>>4, k = tid&15.
    //    Global flat index blk*256+tid -> fully coalesced loads.
    {
        const int gidx = blk * 256 + tid;
        const float w  = W[gidx];
        const float p0 = P[gidx]           + 3.0f;  // axis l
        const float p1 = P[NPK + gidx]     + 3.0f;  // axis i
        const float p2 = P[2 * NPK + gidx] + 3.0f;  // axis j

        const float f0 = floorf(p0), f1 = floorf(p1), f2 = floorf(p2);
        const float r0 = p0 - f0, r1 = p1 - f1, r2 = p2 - f2;
        const int lf  = (int)f0;
        const int if_ = (int)f1;
        const int jf  = (int)f2;

        const float wl[2] = {1.0f - r0, r0};
        const float wi[2] = {1.0f - r1, r1};
        const float wj[2] = {1.0f - r2, r2};

        float* a = &acc[(tid >> 4) * CUBE];

        #pragma unroll
        for (int dl = 0; dl < 2; ++dl) {
            const int l = lf + dl;
            if ((unsigned)l > 6u) continue;
            #pragma unroll
            for (int dj = 0; dj < 2; ++dj) {
                const int j = jf + dj;
                if ((unsigned)j > 6u) continue;
                const float wlj = w * wl[dl] * wj[dj];
                #pragma unroll
                for (int di = 0; di < 2; ++di) {
                    const int i = if_ + di;
                    if ((unsigned)i > 6u) continue;
                    atomicAdd(&a[l * 49 + j * 7 + i], wlj * wi[di]);
                }
            }
        }
    }
    __syncthreads();

    // 3) store own region: flat LDS idx == flat out idx, pure float4 stream.
    float* obase = out + (size_t)blk * (GP * CUBE) + (size_t)wid * 4 * CUBE;
    #pragma unroll
    for (int it = 0; it < 6; ++it) {
        const int idx = lane + it * 64;
        if (it < 5 || idx < 343) {
            const float4 v = *reinterpret_cast<const float4*>(&wacc[idx * 4]);
            *reinterpret_cast<float4*>(&obase[idx * 4]) = v;
        }
    }
}

extern "C" void kernel_launch(void* const* d_in, const int* in_sizes, int n_in,
                              void* d_out, int out_size, void* d_ws, size_t ws_size,
                              hipStream_t stream)
{
    const float* W = (const float*)d_in[0];   // [128,128,16]
    const float* P = (const float*)d_in[1];   // [3,128,128,16]
    float* out = (float*)d_out;               // [128,128,7,7,7]

    const int grid = NPAIR / GP;              // 1024 blocks
    construct3d_scatter<<<grid, 256, 0, stream>>>(W, P, out);
}

// Round 6
// 19.877 us; speedup vs baseline: 1.0564x; 1.0010x over previous
//
#include <hip/hip_runtime.h>

// ConstructKernel3d: trilinear scatter of W into a 7x7x7 cube per (oc,icg) pair.
// out[o,c,l,j,i] = sum_k W[o,c,k] * wA(l; P0) * wB(j; P2) * wC(i; P1)
// Axis weights nonzero only at floor(p)+{0,1}. Scatter <=8 corners per (o,c,k).
//
// Wave-local version: each wave exclusively owns 4 pairs (zero / scatter /
// store all touch only its own 4*343-float LDS region), so no __syncthreads
// is needed -- only same-wave DS ordering via s_waitcnt lgkmcnt(0).

#define OC    128
#define ICG   128
#define KC    16
#define NPAIR (OC * ICG)          // 16384
#define NPK   (NPAIR * KC)        // 262144 elements per P-plane
#define CUBE  343                 // 7*7*7
#define GP    16                  // (o,c) pairs per block -> 256 scatter tasks

__global__ __launch_bounds__(256)
void construct3d_scatter(const float* __restrict__ W,
                         const float* __restrict__ P,
                         float* __restrict__ out)
{
    __shared__ float acc[GP * CUBE];          // 5488 floats = 21952 B
    const int tid  = threadIdx.x;
    const int blk  = blockIdx.x;
    const int wid  = tid >> 6;                // wave 0..3
    const int lane = tid & 63;

    // 0) issue global loads first; latency hides under the zero phase.
    const int gidx = blk * 256 + tid;
    const float w  = W[gidx];
    const float p0 = P[gidx]           + 3.0f;  // axis l
    const float p1 = P[NPK + gidx]     + 3.0f;  // axis i
    const float p2 = P[2 * NPK + gidx] + 3.0f;  // axis j

    float* wacc = &acc[wid * 4 * CUBE];       // this wave's 1372-float region

    // 1) zero own region, float4 (343 float4s per wave)
    const float4 z = {0.f, 0.f, 0.f, 0.f};
    #pragma unroll
    for (int it = 0; it < 6; ++it) {
        const int idx = lane + it * 64;
        if (it < 5 || idx < 343)
            *reinterpret_cast<float4*>(&wacc[idx * 4]) = z;
    }
    asm volatile("s_waitcnt lgkmcnt(0)" ::: "memory");   // zero visible to own atomics

    // 2) scatter: task tid -> local pair p = tid>>4 (within own wave), k = tid&15.
    {
        const float f0 = floorf(p0), f1 = floorf(p1), f2 = floorf(p2);
        const float r0 = p0 - f0, r1 = p1 - f1, r2 = p2 - f2;
        const int lf  = (int)f0;
        const int if_ = (int)f1;
        const int jf  = (int)f2;

        const float wl[2] = {1.0f - r0, r0};
        const float wi[2] = {1.0f - r1, r1};
        const float wj[2] = {1.0f - r2, r2};

        float* a = &acc[(tid >> 4) * CUBE];   // lies inside this wave's region

        #pragma unroll
        for (int dl = 0; dl < 2; ++dl) {
            const int l = lf + dl;
            if ((unsigned)l > 6u) continue;
            #pragma unroll
            for (int dj = 0; dj < 2; ++dj) {
                const int j = jf + dj;
                if ((unsigned)j > 6u) continue;
                const float wlj = w * wl[dl] * wj[dj];
                #pragma unroll
                for (int di = 0; di < 2; ++di) {
                    const int i = if_ + di;
                    if ((unsigned)i > 6u) continue;
                    atomicAdd(&a[l * 49 + j * 7 + i], wlj * wi[di]);
                }
            }
        }
    }
    asm volatile("s_waitcnt lgkmcnt(0)" ::: "memory");   // atomics done before reads

    // 3) store own region: flat LDS idx == flat out idx, pure float4 stream.
    float* obase = out + (size_t)blk * (GP * CUBE) + (size_t)wid * 4 * CUBE;
    #pragma unroll
    for (int it = 0; it < 6; ++it) {
        const int idx = lane + it * 64;
        if (it < 5 || idx < 343) {
            const float4 v = *reinterpret_cast<const float4*>(&wacc[idx * 4]);
            *reinterpret_cast<float4*>(&obase[idx * 4]) = v;
        }
    }
}

extern "C" void kernel_launch(void* const* d_in, const int* in_sizes, int n_in,
                              void* d_out, int out_size, void* d_ws, size_t ws_size,
                              hipStream_t stream)
{
    const float* W = (const float*)d_in[0];   // [128,128,16]
    const float* P = (const float*)d_in[1];   // [3,128,128,16]
    float* out = (float*)d_out;               // [128,128,7,7,7]

    const int grid = NPAIR / GP;              // 1024 blocks
    construct3d_scatter<<<grid, 256, 0, stream>>>(W, P, out);
}